// Round 10
// baseline (138.043 us; speedup 1.0000x reference)
//
#include <hip/hip_runtime.h>
#include <math.h>
#include <string.h>

#define NPTS 200000
#define KNBR 16
#define CDIM 32
#define NITEM (NPTS * KNBR)               // 3,200,000
#define TEMP 0.1f
#define WEIGHT 0.1f
#define EPSV 1e-8f

#define PART_BLOCKS 2048                  // 1024 per dim-group
#define CHUNK (NITEM / 1024)              // 3125 items per partial block
#define BLD_BLOCKS ((NPTS + 255) / 256)   // 782

#define SMP_BLOCKS 625
#define SMP_STRIDE (SMP_BLOCKS * 256)     // 160000 (multiple of 16)
#define SMP_ITER (NITEM / SMP_STRIDE)     // 20

// 4-bit linear quant for dims 30,31: x_hat = (q-7)*QS, q in 0..14
#define QS 0.55f

// ---- workspace layout (256-aligned) ----
#define TBLA_OFF 256
#define TBLB_OFF (TBLA_OFF + NPTS * 16)           // 3,200,256
#define D2A_OFF  (TBLB_OFF + NPTS * 16)           // 6,400,512
#define D2B_OFF  (D2A_OFF + NITEM * 2)            // 12,800,512
#define BL_OFF   (D2B_OFF + NITEM * 2)            // 19,200,512
#define BC_OFF   (BL_OFF + SMP_BLOCKS * 4)
#define WS_NEEDED ((size_t)(BC_OFF + SMP_BLOCKS * 4))

typedef float v2f __attribute__((ext_vector_type(2)));

static __device__ __forceinline__ unsigned short f32_to_f16b(float x) {
    _Float16 h = (_Float16)x;
    unsigned short u;
    __builtin_memcpy(&u, &h, 2);
    return u;
}
static __device__ __forceinline__ float f16b_to_f32(unsigned short u) {
    _Float16 h;
    __builtin_memcpy(&h, &u, 2);
    return (float)h;
}
static __device__ __forceinline__ int q4(float x) {
    int q = (int)rintf(x * (1.0f / QS)) + 7;
    return q < 0 ? 0 : (q > 14 ? 14 : q);
}

// ---------- K1: one thread per point -> tblA row + tblB row ----------------
// tblA: dims 0-15 fp8 (16B). tblB: dims 16-29 fp8 (bytes 0-13),
// dims 30-31 as two 4-bit codes (byte 14), label (byte 15).
__global__ __launch_bounds__(256) void build_tables(
    const float* __restrict__ f, const int* __restrict__ labels,
    unsigned char* __restrict__ A, unsigned char* __restrict__ B) {
    const int p = blockIdx.x * 256 + threadIdx.x;
    if (p >= NPTS) return;
    const float4* fp = (const float4*)(f + (size_t)p * CDIM);
    const float4 v0 = fp[0], v1 = fp[1], v2 = fp[2], v3 = fp[3];
    const float4 v4 = fp[4], v5 = fp[5], v6 = fp[6], v7 = fp[7];

    int a0 = 0, a1 = 0, a2 = 0, a3 = 0;
    a0 = __builtin_amdgcn_cvt_pk_fp8_f32(v0.x, v0.y, a0, false);
    a0 = __builtin_amdgcn_cvt_pk_fp8_f32(v0.z, v0.w, a0, true);
    a1 = __builtin_amdgcn_cvt_pk_fp8_f32(v1.x, v1.y, a1, false);
    a1 = __builtin_amdgcn_cvt_pk_fp8_f32(v1.z, v1.w, a1, true);
    a2 = __builtin_amdgcn_cvt_pk_fp8_f32(v2.x, v2.y, a2, false);
    a2 = __builtin_amdgcn_cvt_pk_fp8_f32(v2.z, v2.w, a2, true);
    a3 = __builtin_amdgcn_cvt_pk_fp8_f32(v3.x, v3.y, a3, false);
    a3 = __builtin_amdgcn_cvt_pk_fp8_f32(v3.z, v3.w, a3, true);
    uint4 ra; ra.x = a0; ra.y = a1; ra.z = a2; ra.w = a3;
    *(uint4*)(A + (size_t)p * 16) = ra;

    int b0 = 0, b1 = 0, b2 = 0, b3 = 0;
    b0 = __builtin_amdgcn_cvt_pk_fp8_f32(v4.x, v4.y, b0, false);
    b0 = __builtin_amdgcn_cvt_pk_fp8_f32(v4.z, v4.w, b0, true);
    b1 = __builtin_amdgcn_cvt_pk_fp8_f32(v5.x, v5.y, b1, false);
    b1 = __builtin_amdgcn_cvt_pk_fp8_f32(v5.z, v5.w, b1, true);
    b2 = __builtin_amdgcn_cvt_pk_fp8_f32(v6.x, v6.y, b2, false);
    b2 = __builtin_amdgcn_cvt_pk_fp8_f32(v6.z, v6.w, b2, true);
    b3 = __builtin_amdgcn_cvt_pk_fp8_f32(v7.x, v7.y, b3, false);  // dims 28,29
    const int pk = q4(v7.z) | (q4(v7.w) << 4);                    // dims 30,31
    b3 = (b3 & 0xffff) | (pk << 16) | ((labels[p] & 0xff) << 24);
    uint4 rb; rb.x = b0; rb.y = b1; rb.z = b2; rb.w = b3;
    *(uint4*)(B + (size_t)p * 16) = rb;
}

// ---------- K2: per-item partial d^2, XCD-grouped; group1 adds posmask -----
// (blockIdx&7)<4 -> XCDs 0-3 -> tblA (dims 0-15); else tblB (dims 16-31+lab).
// Each XCD's random working set = 3.2MB half-table -> L2-resident hits.
__global__ __launch_bounds__(256) void partial_d2(
    const unsigned char* __restrict__ tblA,
    const unsigned char* __restrict__ tblB,
    const int* __restrict__ nbr,
    unsigned short* __restrict__ d2A,
    unsigned short* __restrict__ d2B) {
    const int b = blockIdx.x;
    const int grp = (b >> 2) & 1;
    const int r = (b >> 3) * 4 + (b & 3);          // 0..1023 within group
    const int i0 = r * CHUNK;

    if (grp == 0) {
        for (int t = threadIdx.x; t < CHUNK; t += 256) {
            const int i = i0 + t;
            const int idx = nbr[i];
            const int p = i >> 4;
            const uint4 nv = *(const uint4*)(tblA + (size_t)idx * 16);  // L2 hit
            const uint4 cv = *(const uint4*)(tblA + (size_t)p * 16);
            const unsigned* pn = (const unsigned*)&nv;
            const unsigned* pc = (const unsigned*)&cv;
            float d2 = 0.f;
            #pragma unroll
            for (int q = 0; q < 4; ++q) {
                v2f nl = __builtin_amdgcn_cvt_pk_f32_fp8((int)pn[q], false);
                v2f nh = __builtin_amdgcn_cvt_pk_f32_fp8((int)pn[q], true);
                v2f cl = __builtin_amdgcn_cvt_pk_f32_fp8((int)pc[q], false);
                v2f ch = __builtin_amdgcn_cvt_pk_f32_fp8((int)pc[q], true);
                float a0 = cl.x - nl.x, a1 = cl.y - nl.y;
                float a2 = ch.x - nh.x, a3 = ch.y - nh.y;
                d2 += a0 * a0 + a1 * a1 + a2 * a2 + a3 * a3;
            }
            d2A[i] = f32_to_f16b(d2);
        }
    } else {
        for (int t = threadIdx.x; t < CHUNK; t += 256) {
            const int i = i0 + t;
            const int idx = nbr[i];
            const int p = i >> 4;
            const uint4 nv = *(const uint4*)(tblB + (size_t)idx * 16);  // L2 hit
            const uint4 cv = *(const uint4*)(tblB + (size_t)p * 16);
            const unsigned* pn = (const unsigned*)&nv;
            const unsigned* pc = (const unsigned*)&cv;
            float d2 = 0.f;
            #pragma unroll
            for (int q = 0; q < 3; ++q) {          // dims 16-27 (12 fp8)
                v2f nl = __builtin_amdgcn_cvt_pk_f32_fp8((int)pn[q], false);
                v2f nh = __builtin_amdgcn_cvt_pk_f32_fp8((int)pn[q], true);
                v2f cl = __builtin_amdgcn_cvt_pk_f32_fp8((int)pc[q], false);
                v2f ch = __builtin_amdgcn_cvt_pk_f32_fp8((int)pc[q], true);
                float a0 = cl.x - nl.x, a1 = cl.y - nl.y;
                float a2 = ch.x - nh.x, a3 = ch.y - nh.y;
                d2 += a0 * a0 + a1 * a1 + a2 * a2 + a3 * a3;
            }
            {   // dword3: dims 28,29 (fp8 bytes 0,1)
                v2f nl = __builtin_amdgcn_cvt_pk_f32_fp8((int)pn[3], false);
                v2f cl = __builtin_amdgcn_cvt_pk_f32_fp8((int)pc[3], false);
                float a0 = cl.x - nl.x, a1 = cl.y - nl.y;
                d2 += a0 * a0 + a1 * a1;
            }
            {   // dims 30,31: 4-bit codes in byte 14
                const unsigned nb = (pn[3] >> 16) & 0xffu;
                const unsigned cb = (pc[3] >> 16) & 0xffu;
                const float n30 = (float)(nb & 15u) * QS - 7.0f * QS;
                const float n31 = (float)(nb >> 4) * QS - 7.0f * QS;
                const float c30 = (float)(cb & 15u) * QS - 7.0f * QS;
                const float c31 = (float)(cb >> 4) * QS - 7.0f * QS;
                const float a0 = c30 - n30, a1 = c31 - n31;
                d2 += a0 * a0 + a1 * a1;
            }
            const bool pos = (pn[3] >> 24) == (pc[3] >> 24);    // labels equal
            d2B[i] = (unsigned short)(f32_to_f16b(d2) | (pos ? 0x8000u : 0u));
        }
    }
}

// ---------- K3: pure-stream softmax/mask; per-block plain stores -----------
// No random requests at all: posmask rides d2B's sign bit.
__global__ __launch_bounds__(256) void softmax_part(
    const unsigned short* __restrict__ d2A,
    const unsigned short* __restrict__ d2B,
    float* __restrict__ bl, float* __restrict__ bc) {
    const int tid = threadIdx.x;
    const int lane = tid & 63;
    float loss_acc = 0.f, valid_acc = 0.f;

    for (int k = 0; k < SMP_ITER; ++k) {
        const int i = blockIdx.x * 256 + tid + k * SMP_STRIDE;
        const unsigned short ua = d2A[i];
        const unsigned short ub = d2B[i];
        const bool pos = (ub & 0x8000u) != 0;
        const float d2v = f16b_to_f32(ua) + f16b_to_f32(ub & 0x7fffu);
        const float d = sqrtf(d2v + EPSV);

        float mn = d;
        mn = fminf(mn, __shfl_xor(mn, 1));
        mn = fminf(mn, __shfl_xor(mn, 2));
        mn = fminf(mn, __shfl_xor(mn, 4));
        mn = fminf(mn, __shfl_xor(mn, 8));
        const float e = expf((mn - d) * (1.0f / TEMP));

        float pos_s = pos ? e : 0.f;
        float neg_s = e;
        float cnt_s = pos ? 1.f : 0.f;
        #pragma unroll
        for (int off = 1; off <= 8; off <<= 1) {
            pos_s += __shfl_xor(pos_s, off);
            neg_s += __shfl_xor(neg_s, off);
            cnt_s += __shfl_xor(cnt_s, off);
        }
        if ((lane & 15) == 0) {
            const int icnt = (int)(cnt_s + 0.5f);
            if (icnt > 0 && icnt < KNBR) {
                loss_acc += -logf(pos_s / neg_s + EPSV);
                valid_acc += 1.f;
            }
        }
    }

    loss_acc += __shfl_xor(loss_acc, 16);
    valid_acc += __shfl_xor(valid_acc, 16);
    loss_acc += __shfl_xor(loss_acc, 32);
    valid_acc += __shfl_xor(valid_acc, 32);

    __shared__ float sl[4], sv[4];
    if (lane == 0) { sl[tid >> 6] = loss_acc; sv[tid >> 6] = valid_acc; }
    __syncthreads();
    if (tid == 0) {
        bl[blockIdx.x] = sl[0] + sl[1] + sl[2] + sl[3];   // plain store
        bc[blockIdx.x] = sv[0] + sv[1] + sv[2] + sv[3];
    }
}

// ---------- K4: single-block final reduction -------------------------------
__global__ __launch_bounds__(256) void final_reduce(const float* __restrict__ bl,
                                                    const float* __restrict__ bc,
                                                    float* __restrict__ out) {
    const int tid = threadIdx.x;
    float l = 0.f, v = 0.f;
    for (int i = tid; i < SMP_BLOCKS; i += 256) { l += bl[i]; v += bc[i]; }
    #pragma unroll
    for (int off = 1; off <= 32; off <<= 1) {
        l += __shfl_xor(l, off);
        v += __shfl_xor(v, off);
    }
    __shared__ float sl[4], sv[4];
    if ((tid & 63) == 0) { sl[tid >> 6] = l; sv[tid >> 6] = v; }
    __syncthreads();
    if (tid == 0) {
        const float S = sl[0] + sl[1] + sl[2] + sl[3];
        const float C = sv[0] + sv[1] + sv[2] + sv[3];
        out[0] = S / fmaxf(C, 1.f) * WEIGHT;
    }
}

// ---------------- fp32 direct fallback (tiny ws) ---------------------------
__global__ __launch_bounds__(256) void contrast_fp32(
    const float* __restrict__ features,
    const int* __restrict__ labels,
    const int* __restrict__ nbr,
    float* __restrict__ ws) {
    const int lane = threadIdx.x & 63;
    const int wave = threadIdx.x >> 6;
    const int p0 = blockIdx.x * 16 + wave * 4;
    const int m = lane >> 3;
    const int c = lane & 7;
    const int idx_l = nbr[p0 * KNBR + lane];
    const int labn_l = labels[idx_l];
    const int labc_l = labels[p0 + (lane >> 4)];
    float4 cen[4];
    #pragma unroll
    for (int pt = 0; pt < 4; ++pt)
        cen[pt] = *(const float4*)(features + (size_t)(p0 + pt) * CDIM + c * 4);
    int ridx[8];
    #pragma unroll
    for (int j = 0; j < 8; ++j) ridx[j] = __shfl(idx_l, 8 * j + m);
    float4 v[8];
    #pragma unroll
    for (int j = 0; j < 8; ++j)
        v[j] = *(const float4*)(features + (size_t)ridx[j] * CDIM + c * 4);
    float dj[8];
    #pragma unroll
    for (int j = 0; j < 8; ++j) {
        float4 ce = cen[j >> 1];
        float dx = ce.x - v[j].x, dy = ce.y - v[j].y;
        float dz = ce.z - v[j].z, dw = ce.w - v[j].w;
        float d2 = dx * dx + dy * dy + dz * dz + dw * dw;
        d2 += __shfl_xor(d2, 1);
        d2 += __shfl_xor(d2, 2);
        d2 += __shfl_xor(d2, 4);
        dj[j] = sqrtf(d2 + EPSV);
    }
    float loss_acc = 0.f, valid_acc = 0.f;
    #pragma unroll
    for (int pt = 0; pt < 4; ++pt) {
        float a = dj[2 * pt], b = dj[2 * pt + 1];
        float mn = fminf(a, b);
        mn = fminf(mn, __shfl_xor(mn, 8));
        mn = fminf(mn, __shfl_xor(mn, 16));
        mn = fminf(mn, __shfl_xor(mn, 32));
        const float ea = expf((mn - a) / TEMP);
        const float eb = expf((mn - b) / TEMP);
        const int la = __shfl(labn_l, 16 * pt + m);
        const int lb = __shfl(labn_l, 16 * pt + 8 + m);
        const int lc = __shfl(labc_l, 16 * pt);
        float pos_s = (la == lc ? ea : 0.f) + (lb == lc ? eb : 0.f);
        float neg_s = ea + eb;
        float cnt_s = (la == lc ? 1.f : 0.f) + (lb == lc ? 1.f : 0.f);
        #pragma unroll
        for (int off = 8; off <= 32; off <<= 1) {
            pos_s += __shfl_xor(pos_s, off);
            neg_s += __shfl_xor(neg_s, off);
            cnt_s += __shfl_xor(cnt_s, off);
        }
        if (lane == pt) {
            const int icnt = (int)(cnt_s + 0.5f);
            if (icnt > 0 && icnt < KNBR) {
                loss_acc += -logf(pos_s / neg_s + EPSV);
                valid_acc += 1.f;
            }
        }
    }
    __shared__ float s_loss, s_cnt;
    if (threadIdx.x == 0) { s_loss = 0.f; s_cnt = 0.f; }
    __syncthreads();
    if (lane < 4) { atomicAdd(&s_loss, loss_acc); atomicAdd(&s_cnt, valid_acc); }
    __syncthreads();
    if (threadIdx.x == 0) { atomicAdd(&ws[0], s_loss); atomicAdd(&ws[1], s_cnt); }
}

__global__ void contrast_finalize(const float* __restrict__ ws,
                                  float* __restrict__ out) {
    out[0] = ws[0] / fmaxf(ws[1], 1.f) * WEIGHT;
}

extern "C" void kernel_launch(void* const* d_in, const int* in_sizes, int n_in,
                              void* d_out, int out_size, void* d_ws, size_t ws_size,
                              hipStream_t stream) {
    const float* features = (const float*)d_in[0];
    const int* labels     = (const int*)d_in[1];
    const int* nbr        = (const int*)d_in[2];
    float* out = (float*)d_out;
    float* ws  = (float*)d_ws;

    if (ws_size >= WS_NEEDED) {
        unsigned char* tblA = (unsigned char*)d_ws + TBLA_OFF;
        unsigned char* tblB = (unsigned char*)d_ws + TBLB_OFF;
        unsigned short* d2A = (unsigned short*)((char*)d_ws + D2A_OFF);
        unsigned short* d2B = (unsigned short*)((char*)d_ws + D2B_OFF);
        float* bl = (float*)((char*)d_ws + BL_OFF);
        float* bc = (float*)((char*)d_ws + BC_OFF);

        build_tables<<<BLD_BLOCKS, 256, 0, stream>>>(features, labels, tblA, tblB);
        partial_d2<<<PART_BLOCKS, 256, 0, stream>>>(tblA, tblB, nbr, d2A, d2B);
        softmax_part<<<SMP_BLOCKS, 256, 0, stream>>>(d2A, d2B, bl, bc);
        final_reduce<<<1, 256, 0, stream>>>(bl, bc, out);
    } else {
        hipMemsetAsync(ws, 0, 16, stream);
        contrast_fp32<<<NPTS / 16, 256, 0, stream>>>(features, labels, nbr, ws);
        contrast_finalize<<<1, 1, 0, stream>>>(ws, out);
    }
}

// Round 12
// 134.944 us; speedup vs baseline: 1.0230x; 1.0230x over previous
//
#include <hip/hip_runtime.h>
#include <math.h>
#include <string.h>

#define NPTS 200000
#define KNBR 16
#define CDIM 32
#define NITEM (NPTS * KNBR)               // 3,200,000
#define TEMP 0.1f
#define WEIGHT 0.1f
#define EPSV 1e-8f

#define BLD_BLOCKS ((NPTS + 255) / 256)   // 782

#define PD_BLOCKS 1248                    // 624 blocks per dim-group
#define PD_RANKS 3125                     // rank = 1024 items
#define PD_GSTRIDE 624

#define SMP_BLOCKS 625
#define SMP_ITER 5
#define SMP_STRIDE (SMP_BLOCKS * 1024)    // 640000 (multiple of 16)

// 4-bit linear quant for dims 30,31: x_hat = (q-7)*QS, q in 0..14
#define QS 0.55f

// ---- workspace layout (256-aligned) ----
#define TBLA_OFF 256
#define TBLB_OFF (TBLA_OFF + NPTS * 16)           // 3,200,256
#define D2A_OFF  (TBLB_OFF + NPTS * 16)           // 6,400,512
#define D2B_OFF  (D2A_OFF + NITEM * 2)            // 12,800,512
#define BL_OFF   (D2B_OFF + NITEM * 2)            // 19,200,512
#define BC_OFF   (BL_OFF + SMP_BLOCKS * 4)
#define WS_NEEDED ((size_t)(BC_OFF + SMP_BLOCKS * 4))

typedef float v2f __attribute__((ext_vector_type(2)));
typedef float v4f __attribute__((ext_vector_type(4)));
typedef int   v4i __attribute__((ext_vector_type(4)));
typedef unsigned v4u __attribute__((ext_vector_type(4)));
typedef unsigned v2u __attribute__((ext_vector_type(2)));

static __device__ __forceinline__ unsigned short f32_to_f16b(float x) {
    _Float16 h = (_Float16)x;
    unsigned short u;
    __builtin_memcpy(&u, &h, 2);
    return u;
}
static __device__ __forceinline__ float f16b_to_f32(unsigned short u) {
    _Float16 h;
    __builtin_memcpy(&h, &u, 2);
    return (float)h;
}
static __device__ __forceinline__ int q4(float x) {
    int q = (int)rintf(x * (1.0f / QS)) + 7;
    return q < 0 ? 0 : (q > 14 ? 14 : q);
}

// ---------- K1: one thread per point -> tblA row + tblB row ----------------
// tblA: dims 0-15 fp8 (16B). tblB: dims 16-29 fp8 (bytes 0-13),
// dims 30-31 as two 4-bit codes (byte 14), label (byte 15).
__global__ __launch_bounds__(256) void build_tables(
    const float* __restrict__ f, const int* __restrict__ labels,
    unsigned char* __restrict__ A, unsigned char* __restrict__ B) {
    const int p = blockIdx.x * 256 + threadIdx.x;
    if (p >= NPTS) return;
    const v4f* fp = (const v4f*)(f + (size_t)p * CDIM);
    const v4f v0 = __builtin_nontemporal_load(fp + 0);
    const v4f v1 = __builtin_nontemporal_load(fp + 1);
    const v4f v2 = __builtin_nontemporal_load(fp + 2);
    const v4f v3 = __builtin_nontemporal_load(fp + 3);
    const v4f v4 = __builtin_nontemporal_load(fp + 4);
    const v4f v5 = __builtin_nontemporal_load(fp + 5);
    const v4f v6 = __builtin_nontemporal_load(fp + 6);
    const v4f v7 = __builtin_nontemporal_load(fp + 7);

    int a0 = 0, a1 = 0, a2 = 0, a3 = 0;
    a0 = __builtin_amdgcn_cvt_pk_fp8_f32(v0.x, v0.y, a0, false);
    a0 = __builtin_amdgcn_cvt_pk_fp8_f32(v0.z, v0.w, a0, true);
    a1 = __builtin_amdgcn_cvt_pk_fp8_f32(v1.x, v1.y, a1, false);
    a1 = __builtin_amdgcn_cvt_pk_fp8_f32(v1.z, v1.w, a1, true);
    a2 = __builtin_amdgcn_cvt_pk_fp8_f32(v2.x, v2.y, a2, false);
    a2 = __builtin_amdgcn_cvt_pk_fp8_f32(v2.z, v2.w, a2, true);
    a3 = __builtin_amdgcn_cvt_pk_fp8_f32(v3.x, v3.y, a3, false);
    a3 = __builtin_amdgcn_cvt_pk_fp8_f32(v3.z, v3.w, a3, true);
    v4u ra; ra.x = (unsigned)a0; ra.y = (unsigned)a1;
    ra.z = (unsigned)a2; ra.w = (unsigned)a3;
    *(v4u*)(A + (size_t)p * 16) = ra;

    int b0 = 0, b1 = 0, b2 = 0, b3 = 0;
    b0 = __builtin_amdgcn_cvt_pk_fp8_f32(v4.x, v4.y, b0, false);
    b0 = __builtin_amdgcn_cvt_pk_fp8_f32(v4.z, v4.w, b0, true);
    b1 = __builtin_amdgcn_cvt_pk_fp8_f32(v5.x, v5.y, b1, false);
    b1 = __builtin_amdgcn_cvt_pk_fp8_f32(v5.z, v5.w, b1, true);
    b2 = __builtin_amdgcn_cvt_pk_fp8_f32(v6.x, v6.y, b2, false);
    b2 = __builtin_amdgcn_cvt_pk_fp8_f32(v6.z, v6.w, b2, true);
    b3 = __builtin_amdgcn_cvt_pk_fp8_f32(v7.x, v7.y, b3, false);  // dims 28,29
    const int pk = q4(v7.z) | (q4(v7.w) << 4);                    // dims 30,31
    b3 = (b3 & 0xffff) | (pk << 16) | ((labels[p] & 0xff) << 24);
    v4u rb; rb.x = (unsigned)b0; rb.y = (unsigned)b1;
    rb.z = (unsigned)b2; rb.w = (unsigned)b3;
    *(v4u*)(B + (size_t)p * 16) = rb;
}

// ---------- K2: per-item partial d^2, XCD-grouped, 4 items/thread ----------
// (blockIdx&7)<4 -> XCDs 0-3 -> tblA; else tblB. Streams (nbr, d2) are
// non-temporal so the 3.2MB half-table stays L2-resident.
__global__ __launch_bounds__(256) void partial_d2(
    const unsigned char* __restrict__ tblA,
    const unsigned char* __restrict__ tblB,
    const int* __restrict__ nbr,
    unsigned short* __restrict__ d2A,
    unsigned short* __restrict__ d2B) {
    const int b = blockIdx.x;
    const int grp = (b >> 2) & 1;
    const int r = (b >> 3) * 4 + (b & 3);          // 0..623 within group
    const unsigned char* __restrict__ tbl = grp ? tblB : tblA;
    unsigned short* __restrict__ dst = grp ? d2B : d2A;

    for (int rr = r; rr < PD_RANKS; rr += PD_GSTRIDE) {
        const int i = rr * 1024 + threadIdx.x * 4;   // 4 items, same center
        const v4i idx4 = __builtin_nontemporal_load((const v4i*)(nbr + i));
        const int p = i >> 4;
        const v4u cv = *(const v4u*)(tbl + (size_t)p * 16);   // cached (L1/L2)

        v4u nv[4];
        nv[0] = *(const v4u*)(tbl + (size_t)idx4.x * 16);     // L2-resident hits
        nv[1] = *(const v4u*)(tbl + (size_t)idx4.y * 16);
        nv[2] = *(const v4u*)(tbl + (size_t)idx4.z * 16);
        nv[3] = *(const v4u*)(tbl + (size_t)idx4.w * 16);

        unsigned short o[4];
        if (grp == 0) {
            // decode center once: 16 fp8 dims
            v2f c[8];
            #pragma unroll
            for (int q = 0; q < 4; ++q) {
                c[2 * q]     = __builtin_amdgcn_cvt_pk_f32_fp8((int)cv[q], false);
                c[2 * q + 1] = __builtin_amdgcn_cvt_pk_f32_fp8((int)cv[q], true);
            }
            #pragma unroll
            for (int k = 0; k < 4; ++k) {
                float d2 = 0.f;
                #pragma unroll
                for (int q = 0; q < 4; ++q) {
                    v2f nl = __builtin_amdgcn_cvt_pk_f32_fp8((int)nv[k][q], false);
                    v2f nh = __builtin_amdgcn_cvt_pk_f32_fp8((int)nv[k][q], true);
                    float a0 = c[2 * q].x - nl.x, a1 = c[2 * q].y - nl.y;
                    float a2 = c[2 * q + 1].x - nh.x, a3 = c[2 * q + 1].y - nh.y;
                    d2 += a0 * a0 + a1 * a1 + a2 * a2 + a3 * a3;
                }
                o[k] = f32_to_f16b(d2);
            }
        } else {
            // decode center once: 14 fp8 + 2 q4 + label
            v2f c[7];
            #pragma unroll
            for (int q = 0; q < 3; ++q) {
                c[2 * q]     = __builtin_amdgcn_cvt_pk_f32_fp8((int)cv[q], false);
                c[2 * q + 1] = __builtin_amdgcn_cvt_pk_f32_fp8((int)cv[q], true);
            }
            c[6] = __builtin_amdgcn_cvt_pk_f32_fp8((int)cv[3], false);   // dims 28,29
            const unsigned cb = (cv[3] >> 16) & 0xffu;
            const float c30 = (float)(cb & 15u) * QS - 7.0f * QS;
            const float c31 = (float)(cb >> 4) * QS - 7.0f * QS;
            const unsigned clab = cv[3] >> 24;
            #pragma unroll
            for (int k = 0; k < 4; ++k) {
                float d2 = 0.f;
                #pragma unroll
                for (int q = 0; q < 3; ++q) {          // dims 16-27
                    v2f nl = __builtin_amdgcn_cvt_pk_f32_fp8((int)nv[k][q], false);
                    v2f nh = __builtin_amdgcn_cvt_pk_f32_fp8((int)nv[k][q], true);
                    float a0 = c[2 * q].x - nl.x, a1 = c[2 * q].y - nl.y;
                    float a2 = c[2 * q + 1].x - nh.x, a3 = c[2 * q + 1].y - nh.y;
                    d2 += a0 * a0 + a1 * a1 + a2 * a2 + a3 * a3;
                }
                {   // dims 28,29 (fp8 bytes 0,1 of dword3)
                    v2f nl = __builtin_amdgcn_cvt_pk_f32_fp8((int)nv[k][3], false);
                    float a0 = c[6].x - nl.x, a1 = c[6].y - nl.y;
                    d2 += a0 * a0 + a1 * a1;
                }
                {   // dims 30,31: 4-bit codes in byte 14
                    const unsigned nb = (nv[k][3] >> 16) & 0xffu;
                    const float n30 = (float)(nb & 15u) * QS - 7.0f * QS;
                    const float n31 = (float)(nb >> 4) * QS - 7.0f * QS;
                    const float a0 = c30 - n30, a1 = c31 - n31;
                    d2 += a0 * a0 + a1 * a1;
                }
                const bool pos = (nv[k][3] >> 24) == clab;
                o[k] = (unsigned short)(f32_to_f16b(d2) | (pos ? 0x8000u : 0u));
            }
        }
        v2u pk2;
        pk2.x = (unsigned)o[0] | ((unsigned)o[1] << 16);
        pk2.y = (unsigned)o[2] | ((unsigned)o[3] << 16);
        __builtin_nontemporal_store(pk2, (v2u*)(dst + i));
    }
}

// ---------- K3: pure-stream softmax/mask, 4 items/thread -------------------
// Point = 16 consecutive items = 4 consecutive lanes x 4 in-thread items.
__global__ __launch_bounds__(256) void softmax_part(
    const unsigned short* __restrict__ d2A,
    const unsigned short* __restrict__ d2B,
    float* __restrict__ bl, float* __restrict__ bc) {
    const int tid = threadIdx.x;
    const int lane = tid & 63;
    float loss_acc = 0.f, valid_acc = 0.f;

    for (int k = 0; k < SMP_ITER; ++k) {
        const int i = blockIdx.x * 1024 + tid * 4 + k * SMP_STRIDE;
        const v2u ua = __builtin_nontemporal_load((const v2u*)(d2A + i));
        const v2u ub = __builtin_nontemporal_load((const v2u*)(d2B + i));

        float d[4];
        bool pos[4];
        #pragma unroll
        for (int j = 0; j < 4; ++j) {
            const unsigned short a = (unsigned short)((j < 2 ? ua.x : ua.y) >> ((j & 1) * 16));
            const unsigned short bb = (unsigned short)((j < 2 ? ub.x : ub.y) >> ((j & 1) * 16));
            pos[j] = (bb & 0x8000u) != 0;
            d[j] = sqrtf(f16b_to_f32(a) + f16b_to_f32(bb & 0x7fffu) + EPSV);
        }

        float mn = fminf(fminf(d[0], d[1]), fminf(d[2], d[3]));
        mn = fminf(mn, __shfl_xor(mn, 1));
        mn = fminf(mn, __shfl_xor(mn, 2));     // min over the point's 16 items

        float pos_s = 0.f, neg_s = 0.f, cnt_s = 0.f;
        #pragma unroll
        for (int j = 0; j < 4; ++j) {
            const float e = expf((mn - d[j]) * (1.0f / TEMP));
            neg_s += e;
            if (pos[j]) { pos_s += e; cnt_s += 1.f; }
        }
        #pragma unroll
        for (int off = 1; off <= 2; off <<= 1) {
            pos_s += __shfl_xor(pos_s, off);
            neg_s += __shfl_xor(neg_s, off);
            cnt_s += __shfl_xor(cnt_s, off);
        }
        if ((lane & 3) == 0) {
            const int icnt = (int)(cnt_s + 0.5f);
            if (icnt > 0 && icnt < KNBR) {
                loss_acc += -logf(pos_s / neg_s + EPSV);
                valid_acc += 1.f;
            }
        }
    }

    // holders at lanes 0,4,...,60; fold to lane 0 of the wave
    #pragma unroll
    for (int off = 4; off <= 32; off <<= 1) {
        loss_acc += __shfl_xor(loss_acc, off);
        valid_acc += __shfl_xor(valid_acc, off);
    }

    __shared__ float sl[4], sv[4];
    if (lane == 0) { sl[tid >> 6] = loss_acc; sv[tid >> 6] = valid_acc; }
    __syncthreads();
    if (tid == 0) {
        bl[blockIdx.x] = sl[0] + sl[1] + sl[2] + sl[3];   // plain store
        bc[blockIdx.x] = sv[0] + sv[1] + sv[2] + sv[3];
    }
}

// ---------- K4: single-block final reduction -------------------------------
__global__ __launch_bounds__(256) void final_reduce(const float* __restrict__ bl,
                                                    const float* __restrict__ bc,
                                                    float* __restrict__ out) {
    const int tid = threadIdx.x;
    float l = 0.f, v = 0.f;
    for (int i = tid; i < SMP_BLOCKS; i += 256) { l += bl[i]; v += bc[i]; }
    #pragma unroll
    for (int off = 1; off <= 32; off <<= 1) {
        l += __shfl_xor(l, off);
        v += __shfl_xor(v, off);
    }
    __shared__ float sl[4], sv[4];
    if ((tid & 63) == 0) { sl[tid >> 6] = l; sv[tid >> 6] = v; }
    __syncthreads();
    if (tid == 0) {
        const float S = sl[0] + sl[1] + sl[2] + sl[3];
        const float C = sv[0] + sv[1] + sv[2] + sv[3];
        out[0] = S / fmaxf(C, 1.f) * WEIGHT;
    }
}

// ---------------- fp32 direct fallback (tiny ws) ---------------------------
__global__ __launch_bounds__(256) void contrast_fp32(
    const float* __restrict__ features,
    const int* __restrict__ labels,
    const int* __restrict__ nbr,
    float* __restrict__ ws) {
    const int lane = threadIdx.x & 63;
    const int wave = threadIdx.x >> 6;
    const int p0 = blockIdx.x * 16 + wave * 4;
    const int m = lane >> 3;
    const int c = lane & 7;
    const int idx_l = nbr[p0 * KNBR + lane];
    const int labn_l = labels[idx_l];
    const int labc_l = labels[p0 + (lane >> 4)];
    float4 cen[4];
    #pragma unroll
    for (int pt = 0; pt < 4; ++pt)
        cen[pt] = *(const float4*)(features + (size_t)(p0 + pt) * CDIM + c * 4);
    int ridx[8];
    #pragma unroll
    for (int j = 0; j < 8; ++j) ridx[j] = __shfl(idx_l, 8 * j + m);
    float4 v[8];
    #pragma unroll
    for (int j = 0; j < 8; ++j)
        v[j] = *(const float4*)(features + (size_t)ridx[j] * CDIM + c * 4);
    float dj[8];
    #pragma unroll
    for (int j = 0; j < 8; ++j) {
        float4 ce = cen[j >> 1];
        float dx = ce.x - v[j].x, dy = ce.y - v[j].y;
        float dz = ce.z - v[j].z, dw = ce.w - v[j].w;
        float d2 = dx * dx + dy * dy + dz * dz + dw * dw;
        d2 += __shfl_xor(d2, 1);
        d2 += __shfl_xor(d2, 2);
        d2 += __shfl_xor(d2, 4);
        dj[j] = sqrtf(d2 + EPSV);
    }
    float loss_acc = 0.f, valid_acc = 0.f;
    #pragma unroll
    for (int pt = 0; pt < 4; ++pt) {
        float a = dj[2 * pt], b = dj[2 * pt + 1];
        float mn = fminf(a, b);
        mn = fminf(mn, __shfl_xor(mn, 8));
        mn = fminf(mn, __shfl_xor(mn, 16));
        mn = fminf(mn, __shfl_xor(mn, 32));
        const float ea = expf((mn - a) / TEMP);
        const float eb = expf((mn - b) / TEMP);
        const int la = __shfl(labn_l, 16 * pt + m);
        const int lb = __shfl(labn_l, 16 * pt + 8 + m);
        const int lc = __shfl(labc_l, 16 * pt);
        float pos_s = (la == lc ? ea : 0.f) + (lb == lc ? eb : 0.f);
        float neg_s = ea + eb;
        float cnt_s = (la == lc ? 1.f : 0.f) + (lb == lc ? 1.f : 0.f);
        #pragma unroll
        for (int off = 8; off <= 32; off <<= 1) {
            pos_s += __shfl_xor(pos_s, off);
            neg_s += __shfl_xor(neg_s, off);
            cnt_s += __shfl_xor(cnt_s, off);
        }
        if (lane == pt) {
            const int icnt = (int)(cnt_s + 0.5f);
            if (icnt > 0 && icnt < KNBR) {
                loss_acc += -logf(pos_s / neg_s + EPSV);
                valid_acc += 1.f;
            }
        }
    }
    __shared__ float s_loss, s_cnt;
    if (threadIdx.x == 0) { s_loss = 0.f; s_cnt = 0.f; }
    __syncthreads();
    if (lane < 4) { atomicAdd(&s_loss, loss_acc); atomicAdd(&s_cnt, valid_acc); }
    __syncthreads();
    if (threadIdx.x == 0) { atomicAdd(&ws[0], s_loss); atomicAdd(&ws[1], s_cnt); }
}

__global__ void contrast_finalize(const float* __restrict__ ws,
                                  float* __restrict__ out) {
    out[0] = ws[0] / fmaxf(ws[1], 1.f) * WEIGHT;
}

extern "C" void kernel_launch(void* const* d_in, const int* in_sizes, int n_in,
                              void* d_out, int out_size, void* d_ws, size_t ws_size,
                              hipStream_t stream) {
    const float* features = (const float*)d_in[0];
    const int* labels     = (const int*)d_in[1];
    const int* nbr        = (const int*)d_in[2];
    float* out = (float*)d_out;
    float* ws  = (float*)d_ws;

    if (ws_size >= WS_NEEDED) {
        unsigned char* tblA = (unsigned char*)d_ws + TBLA_OFF;
        unsigned char* tblB = (unsigned char*)d_ws + TBLB_OFF;
        unsigned short* d2A = (unsigned short*)((char*)d_ws + D2A_OFF);
        unsigned short* d2B = (unsigned short*)((char*)d_ws + D2B_OFF);
        float* bl = (float*)((char*)d_ws + BL_OFF);
        float* bc = (float*)((char*)d_ws + BC_OFF);

        build_tables<<<BLD_BLOCKS, 256, 0, stream>>>(features, labels, tblA, tblB);
        partial_d2<<<PD_BLOCKS, 256, 0, stream>>>(tblA, tblB, nbr, d2A, d2B);
        softmax_part<<<SMP_BLOCKS, 256, 0, stream>>>(d2A, d2B, bl, bc);
        final_reduce<<<1, 256, 0, stream>>>(bl, bc, out);
    } else {
        (void)hipMemsetAsync(ws, 0, 16, stream);
        contrast_fp32<<<NPTS / 16, 256, 0, stream>>>(features, labels, nbr, ws);
        contrast_finalize<<<1, 1, 0, stream>>>(ws, out);
    }
}